// Round 1
// baseline (180.107 us; speedup 1.0000x reference)
//
#include <hip/hip_runtime.h>

#define FM_NNZ   819200
#define FM_BATCH 16384
#define FM_K     128

__global__ __launch_bounds__(128) void fm_fwd_kernel(
    const float* __restrict__ vals,
    const int*   __restrict__ row_idx,
    const int*   __restrict__ col_idx,
    const float* __restrict__ w0,
    const float* __restrict__ w,
    const float* __restrict__ v,
    float*       __restrict__ out)
{
    const int row = blockIdx.x;
    const int k   = threadIdx.x;          // latent dim, 0..127

    // --- binary search row segment [start, end) in sorted row_idx ---
    int lo = 0, hi = FM_NNZ;
    while (lo < hi) {
        int mid = (lo + hi) >> 1;
        if (row_idx[mid] < row) lo = mid + 1; else hi = mid;
    }
    const int start = lo;
    hi = FM_NNZ;
    while (lo < hi) {
        int mid = (lo + hi) >> 1;
        if (row_idx[mid] < row + 1) lo = mid + 1; else hi = mid;
    }
    const int end = lo;

    // --- main loop: thread k accumulates latent dim k over the row's nnz ---
    float xv = 0.0f;   // sum_i val_i * v[col_i, k]
    float sq = 0.0f;   // sum_i val_i * v[col_i, k]^2
    #pragma unroll 4
    for (int i = start; i < end; ++i) {
        const float val = vals[i];           // broadcast (same addr all lanes)
        const int   col = col_idx[i];        // broadcast
        const float vk  = v[(size_t)col * FM_K + k];  // coalesced 512B gather
        const float t   = val * vk;
        xv += t;
        sq = fmaf(t, vk, sq);
    }

    // --- linear term: strided over threads ---
    float lin = 0.0f;
    for (int i = start + k; i < end; i += FM_K) {
        lin = fmaf(vals[i], w[col_idx[i]], lin);
    }

    // --- reduce (xv^2 - sq) and lin across 128 threads ---
    float local = fmaf(xv, xv, -sq);
    #pragma unroll
    for (int off = 32; off > 0; off >>= 1) {
        local += __shfl_down(local, off);
        lin   += __shfl_down(lin, off);
    }
    __shared__ float s_local[2], s_lin[2];
    const int wave = threadIdx.x >> 6;
    if ((threadIdx.x & 63) == 0) { s_local[wave] = local; s_lin[wave] = lin; }
    __syncthreads();
    if (threadIdx.x == 0) {
        const float inter = 0.5f * (s_local[0] + s_local[1]);
        const float linear = s_lin[0] + s_lin[1];
        out[row] = w0[0] + linear + inter;
    }
}

extern "C" void kernel_launch(void* const* d_in, const int* in_sizes, int n_in,
                              void* d_out, int out_size, void* d_ws, size_t ws_size,
                              hipStream_t stream) {
    // setup_inputs order: vals, row_idx, col_idx, batch(scalar), w0, w, v
    const float* vals    = (const float*)d_in[0];
    const int*   row_idx = (const int*)  d_in[1];
    const int*   col_idx = (const int*)  d_in[2];
    // d_in[3] = batch (scalar int), compile-time constant here
    const float* w0      = (const float*)d_in[4];
    const float* w       = (const float*)d_in[5];
    const float* v       = (const float*)d_in[6];
    float*       out     = (float*)d_out;

    fm_fwd_kernel<<<FM_BATCH, FM_K, 0, stream>>>(vals, row_idx, col_idx, w0, w, v, out);
}